// Round 1
// baseline (274.986 us; speedup 1.0000x reference)
//
#include <hip/hip_runtime.h>
#include <stdint.h>

#define FP8_MAX 448.0f
// Problem dims (fixed per setup_inputs): B=4, D=64, H=16, N=2048
#define NB 4
#define ND 64
#define NH 16
#define NS 2048

typedef float f32x4 __attribute__((ext_vector_type(4)));

// ---------------------------------------------------------------------------
// Pass 1: per-tensor abs-max.  First half of grid reduces q, second half k.
// Result stored as monotonic uint bits (valid max-order for non-negative f32).
// ---------------------------------------------------------------------------
__global__ __launch_bounds__(256) void amax_kernel(const float* __restrict__ q,
                                                   const float* __restrict__ k,
                                                   unsigned* __restrict__ amax,
                                                   int n4) {
  const int half = gridDim.x >> 1;
  const float4* src;
  unsigned* slot;
  int b;
  if ((int)blockIdx.x < half) { src = (const float4*)q; slot = amax;     b = blockIdx.x; }
  else                        { src = (const float4*)k; slot = amax + 1; b = blockIdx.x - half; }

  float m = 0.f;
  for (int i = b * 256 + threadIdx.x; i < n4; i += half * 256) {
    float4 v = src[i];
    m = fmaxf(m, fmaxf(fmaxf(fabsf(v.x), fabsf(v.y)), fmaxf(fabsf(v.z), fabsf(v.w))));
  }
#pragma unroll
  for (int off = 32; off > 0; off >>= 1)
    m = fmaxf(m, __shfl_xor(m, off, 64));

  __shared__ float red[4];
  if ((threadIdx.x & 63) == 0) red[threadIdx.x >> 6] = m;
  __syncthreads();
  if (threadIdx.x == 0) {
    m = fmaxf(fmaxf(red[0], red[1]), fmaxf(red[2], red[3]));
    atomicMax(slot, __float_as_uint(m));
  }
}

// ---------------------------------------------------------------------------
// Pass 2: quantize to fp8 e4m3 (RNE via v_cvt_pk_fp8_f32) AND repack
//   input  (b, d, h, n)  f32   idx = (b*ND+d)*NH*NS + h*NS + n
//   output (b, h, n, d)  fp8   idx = ((b*NH+h)*NS + n)*ND + d
// Each thread produces 8 consecutive d for one (bh, n): one coalesced 8B store.
// chunk c = bh*(NS*8) + n*8 + dg,  dg selects d0 = dg*8.
// ---------------------------------------------------------------------------
__global__ __launch_bounds__(256) void quant_kernel(const float* __restrict__ in,
                                                    uint2* __restrict__ outp,
                                                    const unsigned* __restrict__ amaxbits) {
  const unsigned c = blockIdx.x * 256 + threadIdx.x;  // [0, 2^20)
  const float amax  = fmaxf(__uint_as_float(*amaxbits), 1e-12f);
  const float scale = FP8_MAX / amax;

  const unsigned bh = c >> 14;           // 2^14 = NS*8
  const unsigned n  = (c >> 3) & (NS - 1);
  const unsigned d0 = (c & 7) * 8;
  const unsigned b  = bh >> 4, h = bh & 15;

  const float* src = in + (size_t)(b * ND + d0) * (NH * NS) + h * NS + n;

  float v[8];
#pragma unroll
  for (int j = 0; j < 8; ++j) {
    float x = src[(size_t)j * (NH * NS)] * scale;
    v[j] = fminf(fmaxf(x, -FP8_MAX), FP8_MAX);
  }
  unsigned lo = 0, hi = 0;
  lo = __builtin_amdgcn_cvt_pk_fp8_f32(v[0], v[1], lo, 0);
  lo = __builtin_amdgcn_cvt_pk_fp8_f32(v[2], v[3], lo, 1);
  hi = __builtin_amdgcn_cvt_pk_fp8_f32(v[4], v[5], hi, 0);
  hi = __builtin_amdgcn_cvt_pk_fp8_f32(v[6], v[7], hi, 1);
  outp[c] = make_uint2(lo, hi);  // byte offset c*8 == ((bh*NS+n)*ND + d0)
}

// ---------------------------------------------------------------------------
// Pass 3: batched GEMM  S[bh][n][m] = sum_d Qp[bh][n][d] * Kp[bh][m][d]
// 128x128 tile per block, 4 waves (2x2, each 64x64 = 4x4 frags of 16x16),
// K = 64 = 2 x mfma_f32_16x16x32_fp8_fp8.  Write-bound: keep staging simple.
// A-frag layout (16x16x32): lane holds row (lane&15), k = (lane>>4)*8 + j.
// C/D layout: col = lane&15, row = (lane>>4)*4 + reg   [guide §3, m89].
// ---------------------------------------------------------------------------
__global__ __launch_bounds__(256) void gemm_kernel(const unsigned char* __restrict__ qp,
                                                   const unsigned char* __restrict__ kp,
                                                   float* __restrict__ out,
                                                   const unsigned* __restrict__ amaxbits) {
  __shared__ __align__(16) unsigned char ldsA[128 * 64];
  __shared__ __align__(16) unsigned char ldsB[128 * 64];

  const int tid  = threadIdx.x;
  const int lane = tid & 63;
  const int wid  = tid >> 6;
  const int wm   = wid >> 1;  // n-quadrant (0..1)
  const int wn   = wid & 1;   // m-quadrant (0..1)

  const int bh = blockIdx.z;
  const int n0 = blockIdx.y * 128;
  const int m0 = blockIdx.x * 128;

  // Each tile is one contiguous 8192B region of the repacked fp8 matrix.
  const unsigned char* Ag = qp + ((size_t)bh * NS + n0) * ND;
  const unsigned char* Bg = kp + ((size_t)bh * NS + m0) * ND;

  // Stage both tiles (512 x 16B granules each, 256 threads x 2)
#pragma unroll
  for (int i = 0; i < 2; ++i) {
    int g = i * 256 + tid;
    ((uint4*)ldsA)[g] = ((const uint4*)Ag)[g];
    ((uint4*)ldsB)[g] = ((const uint4*)Bg)[g];
  }
  __syncthreads();

  const int r16 = lane & 15;
  const int kg  = lane >> 4;

  long long afrag[2][4], bfrag[2][4];
#pragma unroll
  for (int ks = 0; ks < 2; ++ks) {
#pragma unroll
    for (int f = 0; f < 4; ++f) {
      afrag[ks][f] = *(const long long*)&ldsA[(wm * 64 + f * 16 + r16) * ND + ks * 32 + kg * 8];
      bfrag[ks][f] = *(const long long*)&ldsB[(wn * 64 + f * 16 + r16) * ND + ks * 32 + kg * 8];
    }
  }

  f32x4 acc[4][4] = {};
#pragma unroll
  for (int ks = 0; ks < 2; ++ks)
#pragma unroll
    for (int i = 0; i < 4; ++i)
#pragma unroll
      for (int j = 0; j < 4; ++j)
        acc[i][j] = __builtin_amdgcn_mfma_f32_16x16x32_fp8_fp8(afrag[ks][i], bfrag[ks][j],
                                                               acc[i][j], 0, 0, 0);

  // dequant: S = (raw fp8 dot) * amax_q*amax_k/(448^2) / sqrt(64)
  const float aq = fmaxf(__uint_as_float(amaxbits[0]), 1e-12f);
  const float ak = fmaxf(__uint_as_float(amaxbits[1]), 1e-12f);
  const float dq = aq * ak / (FP8_MAX * FP8_MAX * 8.0f);

  float* outbh = out + (size_t)bh * NS * NS;
#pragma unroll
  for (int i = 0; i < 4; ++i) {
    const int nbase = n0 + wm * 64 + i * 16 + kg * 4;
#pragma unroll
    for (int j = 0; j < 4; ++j) {
      const int m = m0 + wn * 64 + j * 16 + r16;
#pragma unroll
      for (int r = 0; r < 4; ++r)
        outbh[(size_t)(nbase + r) * NS + m] = acc[i][j][r] * dq;
    }
  }
}

// ---------------------------------------------------------------------------
extern "C" void kernel_launch(void* const* d_in, const int* in_sizes, int n_in,
                              void* d_out, int out_size, void* d_ws, size_t ws_size,
                              hipStream_t stream) {
  const float* q = (const float*)d_in[0];
  const float* k = (const float*)d_in[1];
  float* out = (float*)d_out;

  // ws layout: [0..7] amax bits (q,k) | @256: fp8 Qp (8MB) | fp8 Kp (8MB)
  unsigned* amax = (unsigned*)d_ws;
  unsigned char* qp = (unsigned char*)d_ws + 256;
  unsigned char* kp = qp + (size_t)NB * NH * NS * ND;  // 8,388,608

  hipMemsetAsync(amax, 0, 8, stream);

  const int n4 = in_sizes[0] / 4;  // float4 count per tensor
  amax_kernel<<<1024, 256, 0, stream>>>(q, k, amax, n4);

  quant_kernel<<<4096, 256, 0, stream>>>(q, (uint2*)qp, amax);
  quant_kernel<<<4096, 256, 0, stream>>>(k, (uint2*)kp, amax + 1);

  dim3 grid(NS / 128, NS / 128, NB * NH);  // (m-tiles, n-tiles, bh)
  gemm_kernel<<<grid, 256, 0, stream>>>(qp, kp, out, amax);
}